// Round 15
// baseline (82.499 us; speedup 1.0000x reference)
//
#include <hip/hip_runtime.h>
#include <hip/hip_bf16.h>
#include <hip/hip_fp16.h>
#include <math.h>

#define T_TOKENS 16384
#define DDIM 2048
#define NEXP 64
#define REFINE_TAU 4e-3f
#define KSPLIT 4
#define KPW (DDIM / KSPLIT)       // 512 k per wave
#define NCHW (KPW / 32)           // 16 chunks of 32-k per wave
#define BLK_TOK 16
#define NBLK (T_TOKENS / BLK_TOK) // 1024 blocks

typedef _Float16 f16x8 __attribute__((ext_vector_type(8)));
typedef float f32x4 __attribute__((ext_vector_type(4)));

// ---------------- Kernel 0: W fp32 -> fp16 panel, wave-linear layout ----------------
// (r,k) -> pw[(((w*16 + c)*4 + mt)*512) + lane*8 + j]; w=k>>9, c=(k>>5)&15,
// mt=r>>4, lane=((k>>3)&3)*16+(r&15), j=k&7.  (same frag mapping verified R4-R14,
// re-blocked so each wave's chunk reads are contiguous 1KB groups)
__global__ __launch_bounds__(256)
void prep_w(const float* __restrict__ W, _Float16* __restrict__ pw) {
    const int t  = blockIdx.x * 256 + threadIdx.x;   // 0..16383
    const int r  = t >> 8;
    const int kc = (t & 255) * 8;
    const float* wp = &W[(size_t)r * DDIM + kc];
    const float4 a = *(const float4*)wp;
    const float4 b = *(const float4*)(wp + 4);
    const float f[8] = { a.x, a.y, a.z, a.w, b.x, b.y, b.z, b.w };
    f16x8 h;
#pragma unroll
    for (int j = 0; j < 8; ++j) h[j] = (_Float16)f[j];
    const int w    = kc >> 9;
    const int c    = (kc >> 5) & 15;
    const int mt   = r >> 4;
    const int lane = (((kc >> 3) & 3) << 4) | (r & 15);
    *(f16x8*)&pw[((((size_t)w * 16 + c) * 4) + mt) * 512 + lane * 8] = h;
}

// ---------------- Kernel 1: forced-pipeline gate GEMM + fused top-2 ----------------
__device__ __forceinline__ bool better(double va, int ia, double vb, int ib) {
    return (va > vb) || (va == vb && ia < ib);
}
__device__ __forceinline__ double dot_f64(const float* __restrict__ xrow,
                                          const float* __restrict__ wr, int lane) {
    double sd = 0.0;
    for (int d = lane; d < DDIM; d += 64)
        sd = fma((double)xrow[d], (double)wr[d], sd);
#pragma unroll
    for (int off = 32; off >= 1; off >>= 1) sd += __shfl_xor(sd, off);
    return sd;
}

// volatile load: fixed program position, forces the register to stay live
#define GLD(dst, p) asm volatile("global_load_dwordx4 %0, %1, off" \
                                 : "=v"(dst) : "v"(p) : "memory")
#define GLDX(c) do { \
    GLD(xr[(c) & 3][0], xsrc + (c) * 32); \
    GLD(xr[(c) & 3][1], xsrc + (c) * 32 + 4); \
} while (0)
#define GLDP(c) do { \
    GLD(pa[(c) & 1][0], pwb + ((c) * 4 + 0) * 512); \
    GLD(pa[(c) & 1][1], pwb + ((c) * 4 + 1) * 512); \
    GLD(pa[(c) & 1][2], pwb + ((c) * 4 + 2) * 512); \
    GLD(pa[(c) & 1][3], pwb + ((c) * 4 + 3) * 512); \
} while (0)
// counted wait + scheduler fence (guide rule #18: sched_barrier right after waitcnt)
#define WAITV(N) do { \
    asm volatile("s_waitcnt vmcnt(" #N ")" ::: "memory"); \
    __builtin_amdgcn_sched_barrier(0); \
} while (0)
#define COMPUTE(c) do { \
    const float4 x0_ = xr[(c) & 3][0]; \
    const float4 x1_ = xr[(c) & 3][1]; \
    f16x8 af_; \
    af_[0] = (_Float16)x0_.x; af_[1] = (_Float16)x0_.y; \
    af_[2] = (_Float16)x0_.z; af_[3] = (_Float16)x0_.w; \
    af_[4] = (_Float16)x1_.x; af_[5] = (_Float16)x1_.y; \
    af_[6] = (_Float16)x1_.z; af_[7] = (_Float16)x1_.w; \
    acc[0] = __builtin_amdgcn_mfma_f32_16x16x32_f16(pa[(c) & 1][0], af_, acc[0], 0, 0, 0); \
    acc[1] = __builtin_amdgcn_mfma_f32_16x16x32_f16(pa[(c) & 1][1], af_, acc[1], 0, 0, 0); \
    acc[2] = __builtin_amdgcn_mfma_f32_16x16x32_f16(pa[(c) & 1][2], af_, acc[2], 0, 0, 0); \
    acc[3] = __builtin_amdgcn_mfma_f32_16x16x32_f16(pa[(c) & 1][3], af_, acc[3], 0, 0, 0); \
} while (0)

__global__ __launch_bounds__(256, 2)   // 2 waves/EU min -> 256-VGPR budget, no spill risk
void gate_fused(const float* __restrict__ x,
                const _Float16* __restrict__ pw,
                const float* __restrict__ W,
                float* __restrict__ out) {
    __shared__ float part[KSPLIT][NEXP][17];   // 17.4 KB

    const int tid  = threadIdx.x;
    const int lane = tid & 63;
    const int w    = tid >> 6;                 // K-slice 0..3
    const int tokb = blockIdx.x * BLK_TOK;

    // x B-frag source: token tokb+(lane&15), k = w*512 + c*32 + (lane>>4)*8
    const float* xsrc = x + (size_t)(tokb + (lane & 15)) * DDIM
                          + (size_t)w * KPW + ((lane >> 4) << 3);
    // W A-frag panel, per-lane base; chunk c, group mt at +((c*4+mt)*512) shorts
    const _Float16* pwb = pw + (size_t)w * 32768 + (size_t)lane * 8;

    f32x4 acc[4] = { {0,0,0,0}, {0,0,0,0}, {0,0,0,0}, {0,0,0,0} };
    float4 xr[4][2];    // x: 4-deep rolling (forced live by asm)
    f16x8 pa[2][4];     // panel: 2-deep rolling

    // prologue issue order: x0 p0 x1 p1 x2 x3  (16 vmcnt units)
    GLDX(0); GLDP(0); GLDX(1); GLDP(1); GLDX(2); GLDX(3);

    // iter c: WAITV(N) -> COMPUTE(c) -> issue x(c+4), p(c+2)
    // N derived from FIFO issue order (see analysis): {10,10,6,...,6,4,4,0}
    WAITV(10); COMPUTE(0);  GLDX(4);  GLDP(2);
    WAITV(10); COMPUTE(1);  GLDX(5);  GLDP(3);
    WAITV(6);  COMPUTE(2);  GLDX(6);  GLDP(4);
    WAITV(6);  COMPUTE(3);  GLDX(7);  GLDP(5);
    WAITV(6);  COMPUTE(4);  GLDX(8);  GLDP(6);
    WAITV(6);  COMPUTE(5);  GLDX(9);  GLDP(7);
    WAITV(6);  COMPUTE(6);  GLDX(10); GLDP(8);
    WAITV(6);  COMPUTE(7);  GLDX(11); GLDP(9);
    WAITV(6);  COMPUTE(8);  GLDX(12); GLDP(10);
    WAITV(6);  COMPUTE(9);  GLDX(13); GLDP(11);
    WAITV(6);  COMPUTE(10); GLDX(14); GLDP(12);
    WAITV(6);  COMPUTE(11); GLDX(15); GLDP(13);
    WAITV(6);  COMPUTE(12);           GLDP(14);
    WAITV(4);  COMPUTE(13);           GLDP(15);
    WAITV(4);  COMPUTE(14);
    WAITV(0);  COMPUTE(15);

    // ---- partials -> LDS (C: col=lane&15=token, row=(lane>>4)*4+j=expert; verified R7-R14) ----
#pragma unroll
    for (int mt = 0; mt < 4; ++mt)
#pragma unroll
        for (int j = 0; j < 4; ++j) {
            const int e = mt * 16 + ((lane >> 4) << 2) + j;
            part[w][e][lane & 15] = acc[mt][j];
        }
    __syncthreads();

    // ---- epilogue: wave w owns 4 tokens; fixed-order K reduction (deterministic) ----
    float* __restrict__ outw = out;
    float* __restrict__ outi = out + (size_t)T_TOKENS * 2;

#pragma unroll 1
    for (int t = 0; t < 4; ++t) {
        const int lt  = w * 4 + t;
        const int tok = tokb + lt;
        const float l = ((part[0][lane][lt] + part[1][lane][lt])
                       + (part[2][lane][lt] + part[3][lane][lt]));

        float v1 = l; int i1 = lane;
#pragma unroll
        for (int off = 32; off >= 1; off >>= 1) {
            const float ov = __shfl_xor(v1, off);
            const int   oi = __shfl_xor(i1, off);
            if (ov > v1 || (ov == v1 && oi < i1)) { v1 = ov; i1 = oi; }
        }
        float v2 = (lane == i1) ? -INFINITY : l; int i2 = lane;
#pragma unroll
        for (int off = 32; off >= 1; off >>= 1) {
            const float ov = __shfl_xor(v2, off);
            const int   oi = __shfl_xor(i2, off);
            if (ov > v2 || (ov == v2 && oi < i2)) { v2 = ov; i2 = oi; }
        }
        float v3 = (lane == i1 || lane == i2) ? -INFINITY : l; int i3 = lane;
#pragma unroll
        for (int off = 32; off >= 1; off >>= 1) {
            const float ov = __shfl_xor(v3, off);
            const int   oi = __shfl_xor(i3, off);
            if (ov > v3 || (ov == v3 && oi < i3)) { v3 = ov; i3 = oi; }
        }

        const float p = expf(l - v1);
        float s = p;
#pragma unroll
        for (int off = 32; off >= 1; off >>= 1) s += __shfl_xor(s, off);

        int iA = i1, iB = i2;
        if ((v1 - v2) < REFINE_TAU || (v2 - v3) < REFINE_TAU) {
            const float* __restrict__ xrow = x + (size_t)tok * DDIM;
            double La = dot_f64(xrow, W + (size_t)i1 * DDIM, lane);
            double Lb = dot_f64(xrow, W + (size_t)i2 * DDIM, lane);
            double Lc = dot_f64(xrow, W + (size_t)i3 * DDIM, lane);
            int ia = i1, ib = i2, ic = i3;
            if (!better(La, ia, Lb, ib)) { double tv = La; La = Lb; Lb = tv; int ti = ia; ia = ib; ib = ti; }
            if (!better(Lb, ib, Lc, ic)) { double tv = Lb; Lb = Lc; Lc = tv; int ti = ib; ib = ic; ic = ti; }
            if (!better(La, ia, Lb, ib)) { double tv = La; La = Lb; Lb = tv; int ti = ia; ia = ib; ib = ti; }
            iA = ia; iB = ib;
        }

        const float pA = __shfl(p, iA);
        const float pB = __shfl(p, iB);
        const float pa_ = pA / s;
        const float pb_ = pB / s;
        const float inv = 1.0f / (pa_ + pb_ + 1e-9f);

        if (lane == 0) {
            const size_t tg2 = (size_t)tok;
            outw[tg2 * 2]     = pa_ * inv;
            outw[tg2 * 2 + 1] = pb_ * inv;
            outi[tg2 * 2]     = (float)iA;
            outi[tg2 * 2 + 1] = (float)iB;
        }
    }
}

extern "C" void kernel_launch(void* const* d_in, const int* in_sizes, int n_in,
                              void* d_out, int out_size, void* d_ws, size_t ws_size,
                              hipStream_t stream) {
    const float* x = (const float*)d_in[0];
    const float* W = (const float*)d_in[1];
    float* out = (float*)d_out;
    _Float16* pw = (_Float16*)d_ws;                 // 256 KB fp16 frag panel

    prep_w<<<NEXP * DDIM / 8 / 256, 256, 0, stream>>>(W, pw);
    gate_fused<<<NBLK, 256, 0, stream>>>(x, pw, W, out);
}

// Round 16
// 53.254 us; speedup vs baseline: 1.5492x; 1.5492x over previous
//
#include <hip/hip_runtime.h>
#include <hip/hip_bf16.h>
#include <hip/hip_fp16.h>
#include <math.h>

#define T_TOKENS 16384
#define DDIM 2048
#define NEXP 64
#define REFINE_TAU 4e-3f
#define KSPLIT 8
#define KPW (DDIM / KSPLIT)       // 256 k per wave
#define NCHW (KPW / 32)           // 8 chunks of 32-k per wave
#define BLK_TOK 16
#define NBLK (T_TOKENS / BLK_TOK) // 1024 blocks

typedef _Float16 f16x8 __attribute__((ext_vector_type(8)));
typedef float f32x4 __attribute__((ext_vector_type(4)));

// ---------------- Kernel 0: W fp32 -> fp16 fragment-ordered panel ----------------
// (r,k) -> pw[((g*64 + ks)*64 + lane)*8 + j], g=r>>4, ks=k>>5,
// lane=((k>>3)&3)*16 + (r&15), j=k&7.  (A-frag mapping, verified R4-R15.)
__global__ __launch_bounds__(256)
void prep_w(const float* __restrict__ W, _Float16* __restrict__ pw) {
    const int t  = blockIdx.x * 256 + threadIdx.x;   // 0..16383
    const int r  = t >> 8;
    const int kc = (t & 255) * 8;
    const float* wp = &W[(size_t)r * DDIM + kc];
    const float4 a = *(const float4*)wp;
    const float4 b = *(const float4*)(wp + 4);
    const float f[8] = { a.x, a.y, a.z, a.w, b.x, b.y, b.z, b.w };
    f16x8 h;
#pragma unroll
    for (int j = 0; j < 8; ++j) h[j] = (_Float16)f[j];
    const int g = r >> 4, ks = kc >> 5;
    const int lane = (((kc >> 3) & 3) << 4) + (r & 15);
    *(f16x8*)&pw[(((size_t)g * 64 + ks) * 64 + lane) * 8] = h;
}

// ---------------- Kernel 1: gate GEMM + fused top-2 (R14 structure, fast refine) ----------------
__device__ __forceinline__ bool better(double va, int ia, double vb, int ib) {
    return (va > vb) || (va == vb && ia < ib);
}

// FAST wave-cooperative f64 dot: 16 coalesced 1KB wave-loads issued up-front,
// 4 independent FMA chains (no serial load->fma->load chain). ~0.4us vs ~4-8us.
__device__ __forceinline__ double dot_f64_fast(const float* __restrict__ xrow,
                                               const float* __restrict__ wr, int lane) {
    float4 xa[8], wa[8];
#pragma unroll
    for (int q = 0; q < 8; ++q) {
        xa[q] = *(const float4*)&xrow[q * 256 + lane * 4];
        wa[q] = *(const float4*)&wr[q * 256 + lane * 4];
    }
    double s0 = 0.0, s1 = 0.0, s2 = 0.0, s3 = 0.0;
#pragma unroll
    for (int q = 0; q < 8; ++q) {
        s0 = fma((double)xa[q].x, (double)wa[q].x, s0);
        s1 = fma((double)xa[q].y, (double)wa[q].y, s1);
        s2 = fma((double)xa[q].z, (double)wa[q].z, s2);
        s3 = fma((double)xa[q].w, (double)wa[q].w, s3);
    }
    double sd = (s0 + s1) + (s2 + s3);
#pragma unroll
    for (int off = 32; off >= 1; off >>= 1) sd += __shfl_xor(sd, off);
    return sd;
}

#define LOADX(slot, c) do { \
    const float* p_ = xsrc + (size_t)(c) * 32; \
    xr[slot][0] = *(const float4*)p_; \
    xr[slot][1] = *(const float4*)(p_ + 4); \
} while (0)

#define LOADP(buf, c) do { \
    _Pragma("unroll") \
    for (int mt_ = 0; mt_ < 4; ++mt_) \
        pa[buf][mt_] = *(const f16x8*)&pw[pbase + (size_t)(c) * 512 + (size_t)mt_ * 32768]; \
} while (0)

#define CHUNK(slot, buf) do { \
    f16x8 af_; \
    af_[0] = (_Float16)xr[slot][0].x; af_[1] = (_Float16)xr[slot][0].y; \
    af_[2] = (_Float16)xr[slot][0].z; af_[3] = (_Float16)xr[slot][0].w; \
    af_[4] = (_Float16)xr[slot][1].x; af_[5] = (_Float16)xr[slot][1].y; \
    af_[6] = (_Float16)xr[slot][1].z; af_[7] = (_Float16)xr[slot][1].w; \
    _Pragma("unroll") \
    for (int mt_ = 0; mt_ < 4; ++mt_) \
        acc[mt_] = __builtin_amdgcn_mfma_f32_16x16x32_f16(pa[buf][mt_], af_, acc[mt_], 0, 0, 0); \
} while (0)

__global__ __launch_bounds__(512, 4)
void gate_fused(const float* __restrict__ x,
                const _Float16* __restrict__ pw,
                const float* __restrict__ W,
                float* __restrict__ out) {
    __shared__ float part[KSPLIT][NEXP][17];   // 34.8 KB

    const int tid  = threadIdx.x;
    const int lane = tid & 63;
    const int w    = tid >> 6;                 // K-slice 0..7
    const int tokb = blockIdx.x * BLK_TOK;

    // x B-frag source: token tokb+(lane&15), k = w*256 + ks*32 + (lane>>4)*8
    const float* xsrc = x + (size_t)(tokb + (lane & 15)) * DDIM
                          + (size_t)w * KPW + ((lane >> 4) << 3);
    // W A-frag panel base for this wave's K-slice
    const size_t pbase = (size_t)w * 4096 + (size_t)lane * 8;

    f32x4 acc[4] = { {0,0,0,0}, {0,0,0,0}, {0,0,0,0}, {0,0,0,0} };
    float4 xr[3][2];
    f16x8 pa[2][4];

    LOADX(0, 0); LOADX(1, 1); LOADX(2, 2);
    LOADP(0, 0);

#pragma unroll
    for (int c = 0; c < NCHW; ++c) {
        if (c + 1 < NCHW) LOADP((c + 1) & 1, c + 1);
        CHUNK(c % 3, c & 1);
        if (c + 3 < NCHW) LOADX((c + 3) % 3, c + 3);
    }

    // ---- partials -> LDS (C: col=lane&15=token, row=(lane>>4)*4+j=expert; verified) ----
#pragma unroll
    for (int mt = 0; mt < 4; ++mt)
#pragma unroll
        for (int j = 0; j < 4; ++j) {
            const int e = mt * 16 + ((lane >> 4) << 2) + j;
            part[w][e][lane & 15] = acc[mt][j];
        }
    __syncthreads();

    // ---- epilogue: wave w owns 2 tokens; fixed-order K reduction (deterministic) ----
    float* __restrict__ outw = out;
    float* __restrict__ outi = out + (size_t)T_TOKENS * 2;

#pragma unroll 1
    for (int t = 0; t < 2; ++t) {
        const int lt  = w * 2 + t;
        const int tok = tokb + lt;
        const float l = (((part[0][lane][lt] + part[1][lane][lt])
                        + (part[2][lane][lt] + part[3][lane][lt]))
                       + ((part[4][lane][lt] + part[5][lane][lt])
                        + (part[6][lane][lt] + part[7][lane][lt])));

        float v1 = l; int i1 = lane;
#pragma unroll
        for (int off = 32; off >= 1; off >>= 1) {
            const float ov = __shfl_xor(v1, off);
            const int   oi = __shfl_xor(i1, off);
            if (ov > v1 || (ov == v1 && oi < i1)) { v1 = ov; i1 = oi; }
        }
        float v2 = (lane == i1) ? -INFINITY : l; int i2 = lane;
#pragma unroll
        for (int off = 32; off >= 1; off >>= 1) {
            const float ov = __shfl_xor(v2, off);
            const int   oi = __shfl_xor(i2, off);
            if (ov > v2 || (ov == v2 && oi < i2)) { v2 = ov; i2 = oi; }
        }
        float v3 = (lane == i1 || lane == i2) ? -INFINITY : l; int i3 = lane;
#pragma unroll
        for (int off = 32; off >= 1; off >>= 1) {
            const float ov = __shfl_xor(v3, off);
            const int   oi = __shfl_xor(i3, off);
            if (ov > v3 || (ov == v3 && oi < i3)) { v3 = ov; i3 = oi; }
        }

        const float p = expf(l - v1);
        float s = p;
#pragma unroll
        for (int off = 32; off >= 1; off >>= 1) s += __shfl_xor(s, off);

        int iA = i1, iB = i2;
        if ((v1 - v2) < REFINE_TAU || (v2 - v3) < REFINE_TAU) {
            const float* __restrict__ xrow = x + (size_t)tok * DDIM;
            double La = dot_f64_fast(xrow, W + (size_t)i1 * DDIM, lane);
            double Lb = dot_f64_fast(xrow, W + (size_t)i2 * DDIM, lane);
            double Lc = dot_f64_fast(xrow, W + (size_t)i3 * DDIM, lane);
            int ia = i1, ib = i2, ic = i3;
            if (!better(La, ia, Lb, ib)) { double tv = La; La = Lb; Lb = tv; int ti = ia; ia = ib; ib = ti; }
            if (!better(Lb, ib, Lc, ic)) { double tv = Lb; Lb = Lc; Lc = tv; int ti = ib; ib = ic; ic = ti; }
            if (!better(La, ia, Lb, ib)) { double tv = La; La = Lb; Lb = tv; int ti = ia; ia = ib; ib = ti; }
            iA = ia; iB = ib;
        }

        const float pA = __shfl(p, iA);
        const float pB = __shfl(p, iB);
        const float pa_ = pA / s;
        const float pb_ = pB / s;
        const float inv = 1.0f / (pa_ + pb_ + 1e-9f);

        if (lane == 0) {
            const size_t tg2 = (size_t)tok;
            outw[tg2 * 2]     = pa_ * inv;
            outw[tg2 * 2 + 1] = pb_ * inv;
            outi[tg2 * 2]     = (float)iA;
            outi[tg2 * 2 + 1] = (float)iB;
        }
    }
}

extern "C" void kernel_launch(void* const* d_in, const int* in_sizes, int n_in,
                              void* d_out, int out_size, void* d_ws, size_t ws_size,
                              hipStream_t stream) {
    const float* x = (const float*)d_in[0];
    const float* W = (const float*)d_in[1];
    float* out = (float*)d_out;
    _Float16* pw = (_Float16*)d_ws;                 // 256 KB fp16 frag panel

    prep_w<<<NEXP * DDIM / 8 / 256, 256, 0, stream>>>(W, pw);
    gate_fused<<<NBLK, 512, 0, stream>>>(x, pw, W, out);
}

// Round 17
// 45.130 us; speedup vs baseline: 1.8280x; 1.1800x over previous
//
#include <hip/hip_runtime.h>
#include <hip/hip_bf16.h>
#include <hip/hip_fp16.h>
#include <math.h>

#define T_TOKENS 16384
#define DDIM 2048
#define NEXP 64
#define REFINE_TAU 4e-3f
#define NCHK 16                    // 16 chunks of 128 k
#define NBLK (T_TOKENS / 16)       // 1024 blocks, 16 tokens each

typedef _Float16 f16x8 __attribute__((ext_vector_type(8)));
typedef float f32x4 __attribute__((ext_vector_type(4)));

__device__ __forceinline__ void gload_lds16(const void* g, void* l) {
    __builtin_amdgcn_global_load_lds(
        (const __attribute__((address_space(1))) void*)g,
        (__attribute__((address_space(3))) void*)l, 16, 0, 0);
}

// ---------------- Kernel 0: W fp32 -> fp16 fragment-ordered panel ----------------
// (r,k) -> pw[((g*64 + ks)*64 + lane)*8 + j], g=r>>4, ks=k>>5,
// lane=((k>>3)&3)*16 + (r&15), j=k&7.  (A-frag mapping, verified R4-R16.)
__global__ __launch_bounds__(256)
void prep_w(const float* __restrict__ W, _Float16* __restrict__ pw) {
    const int t  = blockIdx.x * 256 + threadIdx.x;   // 0..16383
    const int r  = t >> 8;
    const int kc = (t & 255) * 8;
    const float* wp = &W[(size_t)r * DDIM + kc];
    const float4 a = *(const float4*)wp;
    const float4 b = *(const float4*)(wp + 4);
    const float f[8] = { a.x, a.y, a.z, a.w, b.x, b.y, b.z, b.w };
    f16x8 h;
#pragma unroll
    for (int j = 0; j < 8; ++j) h[j] = (_Float16)f[j];
    const int g = r >> 4, ks = kc >> 5;
    const int lane = (((kc >> 3) & 3) << 4) + (r & 15);
    *(f16x8*)&pw[(((size_t)g * 64 + ks) * 64 + lane) * 8] = h;
}

// ---------------- Kernel 1: row-contiguous LDS-staged gate + fused top-2 ----------------
__device__ __forceinline__ bool better(double va, int ia, double vb, int ib) {
    return (va > vb) || (va == vb && ia < ib);
}

// fast wave-cooperative f64 dot (R16-verified): 16 coalesced loads up-front,
// 4 independent FMA chains, then 6-level butterfly.
__device__ __forceinline__ double dot_f64_fast(const float* __restrict__ xrow,
                                               const float* __restrict__ wr, int lane) {
    float4 xa[8], wa[8];
#pragma unroll
    for (int q = 0; q < 8; ++q) {
        xa[q] = *(const float4*)&xrow[q * 256 + lane * 4];
        wa[q] = *(const float4*)&wr[q * 256 + lane * 4];
    }
    double s0 = 0.0, s1 = 0.0, s2 = 0.0, s3 = 0.0;
#pragma unroll
    for (int q = 0; q < 8; ++q) {
        s0 = fma((double)xa[q].x, (double)wa[q].x, s0);
        s1 = fma((double)xa[q].y, (double)wa[q].y, s1);
        s2 = fma((double)xa[q].z, (double)wa[q].z, s2);
        s3 = fma((double)xa[q].w, (double)wa[q].w, s3);
    }
    double sd = (s0 + s1) + (s2 + s3);
#pragma unroll
    for (int off = 32; off >= 1; off >>= 1) sd += __shfl_xor(sd, off);
    return sd;
}

// stage chunk c into xa[buf]: wave w covers rows 4w..4w+3, two 1KB issues.
// Source col pre-swizzled (m173): LDS stays linear, read side applies the XOR.
#define STAGE(buf, c) do { \
    gload_lds16(xs0 + (size_t)(c) * 512, (char*)&xa[buf][0] + (4 * w)     * 512); \
    gload_lds16(xs1 + (size_t)(c) * 512, (char*)&xa[buf][0] + (4 * w + 2) * 512); \
} while (0)

// panel frags for chunk c (4 ksteps), contiguous 1KB wave-loads from L2
#define LOADP(buf, c) do { \
    _Pragma("unroll") \
    for (int ks_ = 0; ks_ < 4; ++ks_) \
        pan[buf][ks_] = *(const f16x8*)&pw[(((size_t)w * 64 + (c) * 4 + ks_) * 64 + lane) * 8]; \
} while (0)

// compute chunk c from xa[buf]: 4 ksteps x 1 MFMA
#define COMPUTE(buf) do { \
    _Pragma("unroll") \
    for (int ks_ = 0; ks_ < 4; ++ks_) { \
        const int col_ = ks_ * 128 + ((lane >> 4) << 5); \
        const f32x4 v0_ = *(const f32x4*)((const char*)&xa[buf][0] + rbase + ((col_)      ^ rswz)); \
        const f32x4 v1_ = *(const f32x4*)((const char*)&xa[buf][0] + rbase + ((col_ + 16) ^ rswz)); \
        f16x8 af_; \
        af_[0] = (_Float16)v0_[0]; af_[1] = (_Float16)v0_[1]; \
        af_[2] = (_Float16)v0_[2]; af_[3] = (_Float16)v0_[3]; \
        af_[4] = (_Float16)v1_[0]; af_[5] = (_Float16)v1_[1]; \
        af_[6] = (_Float16)v1_[2]; af_[7] = (_Float16)v1_[3]; \
        acc = __builtin_amdgcn_mfma_f32_16x16x32_f16(pan[buf][ks_], af_, acc, 0, 0, 0); \
    } \
} while (0)

__global__ __launch_bounds__(256)
void gate_fused(const float* __restrict__ x,
                const _Float16* __restrict__ pw,
                const float* __restrict__ W,
                float* __restrict__ out) {
    __shared__ float xa[2][2048];     // 2 x 8 KB: 16 rows x 512B, XOR-swizzled content
    __shared__ float lg[16][68];      // logits [token][expert], padded

    const int tid  = threadIdx.x;
    const int lane = tid & 63;
    const int w    = tid >> 6;        // expert group 0..3
    const int tokb = blockIdx.x * 16;

    // ---- staging source (per-lane, pre-swizzled column) ----
    // issue j covers rows 4w+2j+(lane>>5); lane slot s=(lane&31)*16 holds global col s^((row&7)<<4)
    const int r0 = 4 * w + (lane >> 5);
    const int r1 = 4 * w + 2 + (lane >> 5);
    const int v0 = ((lane & 31) * 16) ^ ((r0 & 7) << 4);
    const int v1 = ((lane & 31) * 16) ^ ((r1 & 7) << 4);
    const char* xs0 = (const char*)x + (size_t)(tokb + r0) * (DDIM * 4) + v0;
    const char* xs1 = (const char*)x + (size_t)(tokb + r1) * (DDIM * 4) + v1;

    // ---- frag-read geometry: row = lane&15, swizzle on the column part ----
    const int rbase = (lane & 15) * 512;
    const int rswz  = (lane & 7) << 4;

    f16x8 pan[2][4];
    f32x4 acc = { 0.f, 0.f, 0.f, 0.f };

    STAGE(0, 0);
    LOADP(0, 0);
    __syncthreads();                       // chunk 0 landed (vmcnt(0)+lgkmcnt(0) implied)

#pragma unroll
    for (int c = 0; c < NCHK; ++c) {
        if (c + 1 < NCHK) {
            STAGE((c + 1) & 1, c + 1);     // direct-to-LDS, zero VGPR involvement
            LOADP((c + 1) & 1, c + 1);     // L2 panel frags for next chunk
        }
        COMPUTE(c & 1);
        __syncthreads();                   // drains stage; buf swap safe
    }

    // ---- logits -> LDS (C layout verified R12-R16: token=lane&15, expert=(lane>>4)*4+j) ----
    *(f32x4*)&lg[lane & 15][w * 16 + ((lane >> 4) << 2)] = acc;
    __syncthreads();

    // ---- fused epilogue: wave w owns 4 tokens (verified structure + fast refine) ----
    float* __restrict__ outw = out;
    float* __restrict__ outi = out + (size_t)T_TOKENS * 2;

#pragma unroll 1
    for (int t = 0; t < 4; ++t) {
        const int lt  = w * 4 + t;
        const int tok = tokb + lt;
        const float l = lg[lt][lane];

        float v1v = l; int i1 = lane;
#pragma unroll
        for (int off = 32; off >= 1; off >>= 1) {
            const float ov = __shfl_xor(v1v, off);
            const int   oi = __shfl_xor(i1, off);
            if (ov > v1v || (ov == v1v && oi < i1)) { v1v = ov; i1 = oi; }
        }
        float v2v = (lane == i1) ? -INFINITY : l; int i2 = lane;
#pragma unroll
        for (int off = 32; off >= 1; off >>= 1) {
            const float ov = __shfl_xor(v2v, off);
            const int   oi = __shfl_xor(i2, off);
            if (ov > v2v || (ov == v2v && oi < i2)) { v2v = ov; i2 = oi; }
        }
        float v3v = (lane == i1 || lane == i2) ? -INFINITY : l; int i3 = lane;
#pragma unroll
        for (int off = 32; off >= 1; off >>= 1) {
            const float ov = __shfl_xor(v3v, off);
            const int   oi = __shfl_xor(i3, off);
            if (ov > v3v || (ov == v3v && oi < i3)) { v3v = ov; i3 = oi; }
        }

        const float p = expf(l - v1v);
        float s = p;
#pragma unroll
        for (int off = 32; off >= 1; off >>= 1) s += __shfl_xor(s, off);

        int iA = i1, iB = i2;
        if ((v1v - v2v) < REFINE_TAU || (v2v - v3v) < REFINE_TAU) {
            const float* __restrict__ xrow = x + (size_t)tok * DDIM;
            double La = dot_f64_fast(xrow, W + (size_t)i1 * DDIM, lane);
            double Lb = dot_f64_fast(xrow, W + (size_t)i2 * DDIM, lane);
            double Lc = dot_f64_fast(xrow, W + (size_t)i3 * DDIM, lane);
            int ia = i1, ib = i2, ic = i3;
            if (!better(La, ia, Lb, ib)) { double tv = La; La = Lb; Lb = tv; int ti = ia; ia = ib; ib = ti; }
            if (!better(Lb, ib, Lc, ic)) { double tv = Lb; Lb = Lc; Lc = tv; int ti = ib; ib = ic; ic = ti; }
            if (!better(La, ia, Lb, ib)) { double tv = La; La = Lb; Lb = tv; int ti = ia; ia = ib; ib = ti; }
            iA = ia; iB = ib;
        }

        const float pA = __shfl(p, iA);
        const float pB = __shfl(p, iB);
        const float pa_ = pA / s;
        const float pb_ = pB / s;
        const float inv = 1.0f / (pa_ + pb_ + 1e-9f);

        if (lane == 0) {
            const size_t tg2 = (size_t)tok;
            outw[tg2 * 2]     = pa_ * inv;
            outw[tg2 * 2 + 1] = pb_ * inv;
            outi[tg2 * 2]     = (float)iA;
            outi[tg2 * 2 + 1] = (float)iB;
        }
    }
}

extern "C" void kernel_launch(void* const* d_in, const int* in_sizes, int n_in,
                              void* d_out, int out_size, void* d_ws, size_t ws_size,
                              hipStream_t stream) {
    const float* x = (const float*)d_in[0];
    const float* W = (const float*)d_in[1];
    float* out = (float*)d_out;
    _Float16* pw = (_Float16*)d_ws;                 // 256 KB fp16 frag panel

    prep_w<<<NEXP * DDIM / 8 / 256, 256, 0, stream>>>(W, pw);
    gate_fused<<<NBLK, 256, 0, stream>>>(x, pw, W, out);
}